// Round 13
// baseline (3095.237 us; speedup 1.0000x reference)
//
#include <hip/hip_runtime.h>
#include <hip/hip_bf16.h>
#include <math.h>

namespace {

constexpr int B  = 8;
constexpr int N  = 2048;     // power of two: n = p & 2047, b = p >> 11
constexpr int K  = 20;
constexpr int C1 = 64, C2 = 128, C3 = 256;
constexpr int NSLICE = 64;
constexpr double COUNT = 327680.0;   // B*N*K
constexpr double BNEPS = 1e-5;

// ---- workspace layout (bytes) ----
constexpr size_t OFF_IDX1  = 0;                                  // B*N*K int
constexpr size_t OFF_IDX2  = OFF_IDX1 + (size_t)B*N*K*4;         // B*N*K int
constexpr size_t OFF_X1D   = OFF_IDX2 + (size_t)B*N*K*4;         // B*N*C1 f64
constexpr size_t OFF_X2D   = OFF_X1D  + (size_t)B*N*C1*8;        // B*N*C2 f64
constexpr size_t OFF_STATS = OFF_X2D  + (size_t)B*N*C2*8;        // 2*NSLICE*C3 f64
constexpr size_t OFF_MI    = OFF_STATS+ (size_t)2*NSLICE*C3*8;   // 2*C3 f64
constexpr size_t OFF_X2F   = OFF_MI   + 4096;                    // B*N*C2 f32
constexpr size_t OFF_XX2F  = OFF_X2F  + (size_t)B*N*C2*4;        // B*N f32
constexpr size_t OFF_BIG   = OFF_XX2F + (size_t)B*N*4;           // shared big region
// big region, sequential lifetimes: dist f32 (134.2 MB) -> h3 bf16 (167.8 MB
// would not fit beyond dist; h3 bf16 = B*N*K*C3*2 = 167.8MB? no: 8*2048*20*256*2
// = 167,772,160 <= 134,217,728? NO. h3 bf16 is 167.8MB > dist 134.2MB.)
// CORRECTION (kept from r11/r12 which PASSED): h3 bf16 = 8*2048*20*256*2 B.
// 8*2048 = 16384; 16384*20*256 = 83,886,080 elems * 2 B = 167,772,160 B.
// r11/r12 used this same aliasing and passed with ws accommodating it; the
// region extends past dist's 134.2 MB but within ws (proven in r11/r12).

// ---- strict-rounding f32 helpers (block FMA contraction / reassociation) ----
__device__ __forceinline__ float fmul32(float a, float b){ return __fmul_rn(a,b); }
__device__ __forceinline__ float fadd32(float a, float b){ return __fadd_rn(a,b); }
__device__ __forceinline__ float fsub32(float a, float b){ return __fsub_rn(a,b); }

// ---- f32/f64 lane-broadcast via readlane (bit-exact data movement) ----
__device__ __forceinline__ float bcast_f32(float v, int lane) {
  return __int_as_float(__builtin_amdgcn_readlane(__float_as_int(v), lane));
}
__device__ __forceinline__ double bcast_f64(double v, int lane) {
  unsigned long long u = __double_as_longlong(v);
  int hi = __builtin_amdgcn_readlane((int)(u >> 32), lane);
  int lo = __builtin_amdgcn_readlane((int)(u & 0xffffffffu), lane);
  return __longlong_as_double(((unsigned long long)(unsigned)hi << 32) | (unsigned)lo);
}

// ---- per-thread insertion top-20 on f32 (largest, ties keep lowest index) ----
__device__ __forceinline__ void insert_candidatef(float v, int j,
                                                  float (&best)[K], int (&bidx)[K]) {
  if (v > best[K-1]) {
    best[K-1] = v; bidx[K-1] = j;
    #pragma unroll
    for (int i = K-1; i >= 1; --i) {
      if (best[i] > best[i-1]) {
        float tv = best[i]; best[i] = best[i-1]; best[i-1] = tv;
        int   ti = bidx[i]; bidx[i] = bidx[i-1]; bidx[i-1] = ti;
      }
    }
  }
}

// ---- kNN on 3-D coords, numpy-f32-faithful (BIT-FROZEN) ----
__global__ __launch_bounds__(64) void knn_xyz_f32(const float* __restrict__ x,
                                                  int* __restrict__ idxo) {
  int row = blockIdx.x * 64 + threadIdx.x;   // grid = B*N/64
  int b = row >> 11, n = row & (N - 1);
  const float* xb = x + (size_t)b * N * 3;
  float xi0 = xb[(size_t)n*3], xi1 = xb[(size_t)n*3+1], xi2 = xb[(size_t)n*3+2];
  float xxi = fadd32(fadd32(fmul32(xi0,xi0), fmul32(xi1,xi1)), fmul32(xi2,xi2));
  float best[K]; int bidx[K];
  #pragma unroll
  for (int i = 0; i < K; ++i) { best[i] = -INFINITY; bidx[i] = 0; }
  for (int j = 0; j < N; ++j) {
    float a = xb[(size_t)j*3], c = xb[(size_t)j*3+1], d = xb[(size_t)j*3+2];
    float xxj   = fadd32(fadd32(fmul32(a,a), fmul32(c,c)), fmul32(d,d));
    float inner = fadd32(fadd32(fmul32(xi0,a), fmul32(xi1,c)), fmul32(xi2,d));
    float v = fsub32(fsub32(fmul32(2.f, inner), xxi), xxj);
    insert_candidatef(v, j, best, bidx);
  }
  int* o = idxo + (size_t)row * K;
  #pragma unroll
  for (int i = 0; i < K; ++i) o[i] = bidx[i];
}

// ---- x2 -> f32 copy + numpy pairwise(n=128) sum of squares (BIT-FROZEN) ----
__global__ __launch_bounds__(64) void xx2f_kernel(const double* __restrict__ x2d,
                                                  float* __restrict__ x2f,
                                                  float* __restrict__ xx2f) {
  int row = blockIdx.x * 64 + threadIdx.x;   // grid = B*N/64
  const double* src = x2d + (size_t)row * C2;
  float* dst = x2f + (size_t)row * C2;
  float sq[C2];
  #pragma unroll 8
  for (int c = 0; c < C2; ++c) {
    float v = (float)src[c];
    dst[c] = v;
    sq[c] = fmul32(v, v);
  }
  float r0=sq[0], r1=sq[1], r2=sq[2], r3=sq[3], r4=sq[4], r5=sq[5], r6=sq[6], r7=sq[7];
  #pragma unroll
  for (int i = 8; i < 128; i += 8) {
    r0 = fadd32(r0, sq[i+0]); r1 = fadd32(r1, sq[i+1]);
    r2 = fadd32(r2, sq[i+2]); r3 = fadd32(r3, sq[i+3]);
    r4 = fadd32(r4, sq[i+4]); r5 = fadd32(r5, sq[i+5]);
    r6 = fadd32(r6, sq[i+6]); r7 = fadd32(r7, sq[i+7]);
  }
  xx2f[row] = fadd32(fadd32(fadd32(r0,r1), fadd32(r2,r3)),
                     fadd32(fadd32(r4,r5), fadd32(r6,r7)));
}

// ---- all-batch neg-distance matrix, f32 sequential (BIT-FROZEN inner) ----
__global__ __launch_bounds__(256) void dist_f32_kernel(const float* __restrict__ x2f,
                                                       const float* __restrict__ xx2f,
                                                       float* __restrict__ dist) {
  int bz = blockIdx.z;
  const float* x2b  = x2f  + (size_t)bz * N * C2;
  const float* xx2b = xx2f + (size_t)bz * N;
  float* db = dist + (size_t)bz * N * N;
  int ti = blockIdx.y * 64;
  int tj = blockIdx.x * 64;
  int tid = threadIdx.x;
  int tr = tid >> 4, tc = tid & 15;
  __shared__ float A[64][9], Bm[64][9];
  float acc[4][4];
  #pragma unroll
  for (int u = 0; u < 4; ++u)
    #pragma unroll
    for (int v = 0; v < 4; ++v) acc[u][v] = 0.f;
  for (int c0 = 0; c0 < C2; c0 += 8) {
    for (int i = tid; i < 512; i += 256) {
      int r = i >> 3, c = i & 7;
      A[r][c]  = x2b[(size_t)(ti + r)*C2 + c0 + c];
      Bm[r][c] = x2b[(size_t)(tj + r)*C2 + c0 + c];
    }
    __syncthreads();
    #pragma unroll
    for (int c = 0; c < 8; ++c) {       // ascending c: exact sequential order
      float a[4], bv[4];
      #pragma unroll
      for (int u = 0; u < 4; ++u) a[u] = A[tr*4 + u][c];
      #pragma unroll
      for (int v = 0; v < 4; ++v) bv[v] = Bm[tc*4 + v][c];
      #pragma unroll
      for (int u = 0; u < 4; ++u)
        #pragma unroll
        for (int v = 0; v < 4; ++v)
          acc[u][v] = fadd32(acc[u][v], fmul32(a[u], bv[v]));
    }
    __syncthreads();
  }
  #pragma unroll
  for (int u = 0; u < 4; ++u) {
    int i = ti + tr*4 + u;
    float xxi = xx2b[i];
    #pragma unroll
    for (int v = 0; v < 4; ++v) {
      int j = tj + tc*4 + v;
      db[(size_t)i*N + j] = fsub32(fsub32(fmul32(2.f, acc[u][v]), xxi), xx2b[j]);
    }
  }
}

// ---- wave-parallel top-20 on frozen dist values (coalesced reads) ----
__global__ __launch_bounds__(256) void knn_feat_wave(const float* __restrict__ dist,
                                                     int* __restrict__ idxo) {
  int row  = blockIdx.x * 4 + (threadIdx.x >> 6);   // grid = B*N/4
  int lane = threadIdx.x & 63;
  const float* dr = dist + (size_t)row * N;
  float vals[32];
  #pragma unroll
  for (int t = 0; t < 32; ++t) vals[t] = dr[lane + (t << 6)];   // coalesced
  int* out = idxo + (size_t)row * K;
  for (int sel = 0; sel < K; ++sel) {
    float best = -INFINITY; int bt = 0;
    #pragma unroll
    for (int t = 0; t < 32; ++t)
      if (vals[t] > best) { best = vals[t]; bt = t; }
    int bcol = lane + (bt << 6);
    #pragma unroll
    for (int off = 32; off >= 1; off >>= 1) {
      float ov = __shfl_xor(best, off, 64);
      int   oc = __shfl_xor(bcol, off, 64);
      if (ov > best || (ov == best && oc < bcol)) { best = ov; bcol = oc; }
    }
    if (lane == 0) out[sel] = bcol;
    int kill = ((bcol & 63) == lane) ? (bcol >> 6) : 32;
    #pragma unroll
    for (int t = 0; t < 32; ++t) if (t == kill) vals[t] = -INFINITY;
  }
}

// ---- layer 1 (two-pass, f64): geometry + conv1 (BIT-FROZEN) ----
template<int PASS>
__global__ __launch_bounds__(64) void l1_kernel(
    const float* __restrict__ x, const float* __restrict__ nrm,
    const float* __restrict__ w1, const int* __restrict__ idx1,
    double* __restrict__ sS, double* __restrict__ sQ,
    const double* __restrict__ mid, const float* __restrict__ g1, const float* __restrict__ b1,
    double* __restrict__ x1d, float* __restrict__ out448,
    float* __restrict__ outR1, float* __restrict__ outR2) {
  int p = blockIdx.x;
  int tid = threadIdx.x;
  int b = p >> 11, n = p & (N - 1);
  __shared__ float  wl[C1 * 9];
  __shared__ double rotd[K][3];
  __shared__ double fld[K][9];
  for (int i = tid; i < C1 * 9; i += 64) wl[i] = w1[i];
  const float* xb = x + (size_t)b * N * 3;
  double nx = nrm[(size_t)p*3], ny = nrm[(size_t)p*3+1], nz = nrm[(size_t)p*3+2];
  double vx = ny, vy = -nx;
  double s = 1.0 / fmax(1.0 + nz, 1e-8);
  double vxy = vx * vy;
  double R1v[9];
  R1v[0] = 1.0 - s*(vy*vy); R1v[1] = s*vxy;           R1v[2] = vy;
  R1v[3] = s*vxy;           R1v[4] = 1.0 - s*(vx*vx); R1v[5] = -vx;
  R1v[6] = -vy;             R1v[7] = vx;              R1v[8] = 1.0 - s*(vx*vx + vy*vy);
  double xi0 = xb[(size_t)n*3], xi1 = xb[(size_t)n*3+1], xi2 = xb[(size_t)n*3+2];
  if (tid < K) {
    int j = idx1[(size_t)p*K + tid];
    double d0 = (double)xb[(size_t)j*3]   - xi0;
    double d1 = (double)xb[(size_t)j*3+1] - xi1;
    double d2 = (double)xb[(size_t)j*3+2] - xi2;
    rotd[tid][0] = R1v[0]*d0 + R1v[1]*d1 + R1v[2]*d2;
    rotd[tid][1] = R1v[3]*d0 + R1v[4]*d1 + R1v[5]*d2;
    rotd[tid][2] = R1v[6]*d0 + R1v[7]*d1 + R1v[8]*d2;
  }
  __syncthreads();
  double mx = 0.0, my = 0.0;
  #pragma unroll
  for (int k = 0; k < K; ++k) { mx += rotd[k][0]; my += rotd[k][1]; }
  mx /= 20.0; my /= 20.0;
  double r = sqrt(mx*mx + my*my);
  double ct = 1.0, st = 0.0;
  if (r > 0.0) { ct = mx / r; st = my / r; }   // cos/sin of atan2(my,mx)
  if (tid < K) {
    double r0 = rotd[tid][0], r1 = rotd[tid][1], r2 = rotd[tid][2];
    double a0 = ct*r0 + st*r1;
    double a1 = ct*r1 - st*r0;
    fld[tid][0] = a0;  fld[tid][1] = a1;   fld[tid][2] = r2;
    fld[tid][3] = a0;  fld[tid][4] = -a1;  fld[tid][5] = r2;   // xz-mirror
    fld[tid][6] = xi0; fld[tid][7] = xi1;  fld[tid][8] = xi2;  // x_rep
  }
  if (PASS == 0 && tid == 0) {
    float* o1 = outR1 + (size_t)p * 9;
    #pragma unroll
    for (int i = 0; i < 9; ++i) o1[i] = (float)R1v[i];
    float* o2 = outR2 + (size_t)p * 9;
    o2[0] = (float)ct;  o2[1] = (float)st; o2[2] = 0.f;
    o2[3] = (float)-st; o2[4] = (float)ct; o2[5] = 0.f;
    o2[6] = 0.f;        o2[7] = 0.f;       o2[8] = 1.f;
  }
  __syncthreads();
  int o = tid;
  if (PASS == 0) {
    double sum = 0., sq = 0.;
    #pragma unroll
    for (int k = 0; k < K; ++k) {
      double h = 0.;
      #pragma unroll
      for (int c = 0; c < 9; ++c) h = fma((double)wl[o*9 + c], fld[k][c], h);
      sum += h; sq += h*h;
    }
    int slice = p & (NSLICE - 1);
    atomicAdd(&sS[slice*C3 + o], sum);
    atomicAdd(&sQ[slice*C3 + o], sq);
  } else {
    double m = mid[o], is = mid[C3 + o];
    double g = g1[o], bb = b1[o];
    double mxv = -INFINITY;
    #pragma unroll
    for (int k = 0; k < K; ++k) {
      double h = 0.;
      #pragma unroll
      for (int c = 0; c < 9; ++c) h = fma((double)wl[o*9 + c], fld[k][c], h);
      double y = ((h - m) * is) * g + bb;
      y = y > 0.0 ? y : 0.2 * y;
      mxv = fmax(mxv, y);
    }
    x1d[(size_t)p*C1 + o] = mxv;
    out448[(size_t)p*448 + o] = (float)mxv;
  }
}

// ---- conv2 core v2: readlane-broadcast dif (bit-identical products/order).
// lane owns dif[k][lane] (one f64 per k, 40 VGPR). Phase1: c ascending via
// bcast_f64; phase2: identical to r12 (LDS xiv). 128 threads. ----
__device__ __forceinline__ void conv2_core(const double* __restrict__ x1d,
                                           const int* __restrict__ idx,
                                           const float* __restrict__ w,
                                           int p, int tid, double (&acc)[K]) {
  int b = p >> 11;
  int lane = tid & 63;
  __shared__ double xiL[C1];
  __shared__ int jidx[K];
  if (tid < K) jidx[tid] = idx[(size_t)p*K + tid];
  if (tid < C1) xiL[tid] = x1d[(size_t)p*C1 + tid];
  __syncthreads();
  // lane-owned dif: same f64 subtraction as difL[k][lane] in r12
  double xi_lane = x1d[(size_t)p*C1 + lane];
  double xrd[K];
  #pragma unroll
  for (int k = 0; k < K; ++k)
    xrd[k] = x1d[((size_t)b*N + jidx[k])*C1 + lane] - xi_lane;
  const float* wr = w + (size_t)tid * (2*C1);
  #pragma unroll
  for (int k = 0; k < K; ++k) acc[k] = 0.0;
  // phase 1: diff operand, c ascending per acc (bit-identical order)
  #pragma unroll 1
  for (int c0 = 0; c0 < C1; c0 += 8) {
    double wd[8];
    #pragma unroll
    for (int i = 0; i < 8; ++i) wd[i] = (double)wr[c0+i];
    #pragma unroll
    for (int k = 0; k < K; ++k) {
      #pragma unroll
      for (int i = 0; i < 8; ++i) {
        double dv = bcast_f64(xrd[k], c0 + i);
        acc[k] = fma(wd[i], dv, acc[k]);
      }
    }
  }
  // phase 2: x_rep operand, c ascending per acc (verbatim r12)
  #pragma unroll
  for (int c0 = 0; c0 < C1; c0 += 16) {
    double wd[16], xiv[16];
    #pragma unroll
    for (int i = 0; i < 16; ++i) { wd[i] = (double)wr[C1+c0+i]; xiv[i] = xiL[c0+i]; }
    #pragma unroll
    for (int k = 0; k < K; ++k) {
      #pragma unroll
      for (int i = 0; i < 16; ++i) acc[k] = fma(wd[i], xiv[i], acc[k]);
    }
  }
}

// ---- conv2 (two-pass recompute) ----
template<int PASS>
__global__ __launch_bounds__(128, 1) void conv2_full(
    const double* __restrict__ x1d, const int* __restrict__ idx,
    const float* __restrict__ w,
    double* __restrict__ sS, double* __restrict__ sQ,
    const double* __restrict__ mid, const float* __restrict__ gam, const float* __restrict__ bet,
    double* __restrict__ x2d, float* __restrict__ out448) {
  int p = blockIdx.x;
  int tid = threadIdx.x;
  double acc[K];
  conv2_core(x1d, idx, w, p, tid, acc);
  if (PASS == 0) {
    double sum = 0., sq = 0.;
    #pragma unroll
    for (int k = 0; k < K; ++k) { sum += acc[k]; sq += acc[k]*acc[k]; }
    int slice = p & (NSLICE - 1);
    atomicAdd(&sS[slice*C3 + tid], sum);
    atomicAdd(&sQ[slice*C3 + tid], sq);
  } else {
    double m = mid[tid], is = mid[C3 + tid];
    double g = gam[tid], bb = bet[tid];
    double mxv = -INFINITY;
    #pragma unroll
    for (int k = 0; k < K; ++k) {
      double y = ((acc[k] - m) * is) * g + bb;
      y = y > 0.0 ? y : 0.2 * y;
      mxv = fmax(mxv, y);
    }
    x2d[(size_t)p*C2 + tid] = mxv;
    out448[(size_t)p*448 + C1 + tid] = (float)mxv;
  }
}

// ---- conv3 pass0 v2: readlane-broadcast xj. lane owns xr[t] =
// xj[t>>1][((t&1)<<6)+lane], t=0..39 (coalesced gather, no LDS xj).
// Per-acc fmaf order unchanged (c ascending) -> bit-identical h3/stats. ----
__global__ __launch_bounds__(256, 1) void conv3_p0_store(
    const float* __restrict__ x2f, const int* __restrict__ idx,
    const float* __restrict__ w,
    double* __restrict__ sS, double* __restrict__ sQ,
    __hip_bfloat16* __restrict__ h3) {
  int p = blockIdx.x;
  int tid = threadIdx.x;
  int lane = tid & 63;
  int b = p >> 11;
  __shared__ float xiL[C2];
  __shared__ int jidx[K];
  if (tid < K) jidx[tid] = idx[(size_t)p*K + tid];
  if (tid < C2) xiL[tid] = x2f[(size_t)p*C2 + tid];
  __syncthreads();
  float xr[2*K];
  #pragma unroll
  for (int t = 0; t < 2*K; ++t) {
    int row = t >> 1, off = ((t & 1) << 6) + lane;
    xr[t] = x2f[((size_t)b*N + jidx[row])*C2 + off];
  }
  const float* wr = w + (size_t)tid * (2*C2);
  float base = 0.f;
  #pragma unroll
  for (int c0 = 0; c0 < C2; c0 += 32) {
    #pragma unroll
    for (int i = 0; i < 32; ++i)
      base = fmaf(wr[C2+c0+i] - wr[c0+i], xiL[c0+i], base);
  }
  float acc[K];
  #pragma unroll
  for (int k = 0; k < K; ++k) acc[k] = base;
  // half 1: c in [0,64) -> xr[2k], lane index c
  #pragma unroll 1
  for (int c0 = 0; c0 < 64; c0 += 8) {
    float wd[8];
    #pragma unroll
    for (int i = 0; i < 8; ++i) wd[i] = wr[c0+i];
    #pragma unroll
    for (int k = 0; k < K; ++k) {
      #pragma unroll
      for (int i = 0; i < 8; ++i) {
        float s = bcast_f32(xr[2*k], c0 + i);
        acc[k] = fmaf(wd[i], s, acc[k]);
      }
    }
  }
  // half 2: c in [64,128) -> xr[2k+1], lane index c-64
  #pragma unroll 1
  for (int c0 = 64; c0 < 128; c0 += 8) {
    float wd[8];
    #pragma unroll
    for (int i = 0; i < 8; ++i) wd[i] = wr[c0+i];
    #pragma unroll
    for (int k = 0; k < K; ++k) {
      #pragma unroll
      for (int i = 0; i < 8; ++i) {
        float s = bcast_f32(xr[2*k + 1], c0 + i - 64);
        acc[k] = fmaf(wd[i], s, acc[k]);
      }
    }
  }
  double sum = 0., sq = 0.;
  __hip_bfloat16* hb = h3 + (size_t)p * K * C3;
  #pragma unroll
  for (int k = 0; k < K; ++k) {
    double h = (double)acc[k];
    sum += h; sq += h*h;
    hb[k*C3 + tid] = __float2bfloat16(acc[k]);
  }
  int slice = p & (NSLICE - 1);
  atomicAdd(&sS[slice*C3 + tid], sum);
  atomicAdd(&sQ[slice*C3 + tid], sq);
}

// ---- conv3 pass1: load bf16 h3 + BN + max (r11/r12-proven) ----
__global__ __launch_bounds__(256, 1) void conv3_p1_load(
    const __hip_bfloat16* __restrict__ h3, const double* __restrict__ mid,
    const float* __restrict__ gam, const float* __restrict__ bet,
    float* __restrict__ out448) {
  int p = blockIdx.x;
  int o = threadIdx.x;
  float m = (float)mid[o], is = (float)mid[C3 + o];
  float g = gam[o], bb = bet[o];
  const __hip_bfloat16* hb = h3 + (size_t)p * K * C3;
  float mxv = -INFINITY;
  #pragma unroll
  for (int k = 0; k < K; ++k) {
    float h = __bfloat162float(hb[k*C3 + o]);
    float y = (h - m) * is * g + bb;
    y = y > 0.f ? y : 0.2f * y;
    mxv = fmaxf(mxv, y);
  }
  out448[(size_t)p*448 + C1 + C2 + o] = mxv;
}

// ---- finalize BN stats (f64) ----
__global__ void finalize_stats(const double* __restrict__ sS, const double* __restrict__ sQ,
                               double* __restrict__ mid, int C) {
  int o = threadIdx.x;
  if (o >= C) return;
  double s = 0., q = 0.;
  for (int i = 0; i < NSLICE; ++i) { s += sS[i*C3 + o]; q += sQ[i*C3 + o]; }
  double m = s / COUNT;
  double v = q / COUNT - m*m;
  mid[o] = m;
  mid[C3 + o] = 1.0 / sqrt(v + BNEPS);
}

} // namespace

extern "C" void kernel_launch(void* const* d_in, const int* in_sizes, int n_in,
                              void* d_out, int out_size, void* d_ws, size_t ws_size,
                              hipStream_t stream) {
  (void)in_sizes; (void)n_in; (void)out_size; (void)ws_size;
  const float* x   = (const float*)d_in[0];
  const float* nrm = (const float*)d_in[1];
  const float* w1  = (const float*)d_in[2];
  const float* g1  = (const float*)d_in[3];
  const float* b1  = (const float*)d_in[4];
  const float* w2  = (const float*)d_in[5];
  const float* g2  = (const float*)d_in[6];
  const float* b2  = (const float*)d_in[7];
  const float* w3  = (const float*)d_in[8];
  const float* g3  = (const float*)d_in[9];
  const float* b3  = (const float*)d_in[10];
  float* out = (float*)d_out;
  char*  ws  = (char*)d_ws;

  int*    idx1 = (int*)(ws + OFF_IDX1);
  int*    idx2 = (int*)(ws + OFF_IDX2);
  double* x1d  = (double*)(ws + OFF_X1D);
  double* x2d  = (double*)(ws + OFF_X2D);
  double* sS   = (double*)(ws + OFF_STATS);
  double* sQ   = sS + (size_t)NSLICE * C3;
  double* mid  = (double*)(ws + OFF_MI);
  float*  x2f  = (float*)(ws + OFF_X2F);
  float*  xx2f = (float*)(ws + OFF_XX2F);
  char*   big  = ws + OFF_BIG;
  float*  dist = (float*)big;                 // live: dist_f32 .. knn_feat
  __hip_bfloat16* h3 = (__hip_bfloat16*)big;  // live: conv3_p0 .. conv3_p1 (dist dead)

  float* outR1 = out + (size_t)B * N * 448;
  float* outR2 = outR1 + (size_t)B * N * 9;

  // kNN1 — numpy-f32-faithful formula
  knn_xyz_f32<<<B*N/64, 64, 0, stream>>>(x, idx1);

  // layer 1 (f64 two-pass)
  hipMemsetAsync(sS, 0, (size_t)2*NSLICE*C3*sizeof(double), stream);
  l1_kernel<0><<<B*N, 64, 0, stream>>>(x, nrm, w1, idx1, sS, sQ, nullptr, nullptr, nullptr,
                                       nullptr, nullptr, outR1, outR2);
  finalize_stats<<<1, C3, 0, stream>>>(sS, sQ, mid, C1);
  l1_kernel<1><<<B*N, 64, 0, stream>>>(x, nrm, w1, idx1, nullptr, nullptr, mid, g1, b1,
                                       x1d, out, outR1, outR2);

  // layer 2 (f64 two-pass recompute, bit-exact op order, readlane broadcast)
  hipMemsetAsync(sS, 0, (size_t)2*NSLICE*C3*sizeof(double), stream);
  conv2_full<0><<<B*N, 128, 0, stream>>>(x1d, idx1, w2, sS, sQ, nullptr, nullptr, nullptr,
                                         nullptr, nullptr);
  finalize_stats<<<1, C3, 0, stream>>>(sS, sQ, mid, C2);
  conv2_full<1><<<B*N, 128, 0, stream>>>(x1d, idx1, w2, nullptr, nullptr, mid, g2, b2,
                                         x2d, out);

  // kNN2 — numpy-f32-faithful, all batches fused; wave-parallel coalesced top-k
  xx2f_kernel<<<B*N/64, 64, 0, stream>>>(x2d, x2f, xx2f);
  dist_f32_kernel<<<dim3(N/64, N/64, B), 256, 0, stream>>>(x2f, xx2f, dist);
  knn_feat_wave<<<B*N/4, 256, 0, stream>>>(dist, idx2);

  // layer 3 (f32 conv once via readlane + bf16 h3 + light BN/max)
  hipMemsetAsync(sS, 0, (size_t)2*NSLICE*C3*sizeof(double), stream);
  conv3_p0_store<<<B*N, 256, 0, stream>>>(x2f, idx2, w3, sS, sQ, h3);
  finalize_stats<<<1, C3, 0, stream>>>(sS, sQ, mid, C3);
  conv3_p1_load<<<B*N, 256, 0, stream>>>(h3, mid, g3, b3, out);
}

// Round 14
// 2222.933 us; speedup vs baseline: 1.3924x; 1.3924x over previous
//
#include <hip/hip_runtime.h>
#include <hip/hip_bf16.h>
#include <math.h>

namespace {

constexpr int B  = 8;
constexpr int N  = 2048;     // power of two: n = p & 2047, b = p >> 11
constexpr int K  = 20;
constexpr int C1 = 64, C2 = 128, C3 = 256;
constexpr int NSLICE = 64;
constexpr double COUNT = 327680.0;   // B*N*K
constexpr double BNEPS = 1e-5;

// ---- workspace layout (bytes) ----
constexpr size_t OFF_IDX1  = 0;                                  // B*N*K int
constexpr size_t OFF_IDX2  = OFF_IDX1 + (size_t)B*N*K*4;         // B*N*K int
constexpr size_t OFF_X1D   = OFF_IDX2 + (size_t)B*N*K*4;         // B*N*C1 f64
constexpr size_t OFF_X2D   = OFF_X1D  + (size_t)B*N*C1*8;        // B*N*C2 f64
constexpr size_t OFF_STATS = OFF_X2D  + (size_t)B*N*C2*8;        // 2*NSLICE*C3 f64
constexpr size_t OFF_MI    = OFF_STATS+ (size_t)2*NSLICE*C3*8;   // 2*C3 f64
constexpr size_t OFF_X2F   = OFF_MI   + 4096;                    // B*N*C2 f32
constexpr size_t OFF_XX2F  = OFF_X2F  + (size_t)B*N*C2*4;        // B*N f32
constexpr size_t OFF_BIG   = OFF_XX2F + (size_t)B*N*4;           // shared big region
// big region, sequential lifetimes: dist f32 (134.2 MB), then h3 bf16
// (167.8 MB) — both within ws (proven to fit in r11/r12).

// ---- strict-rounding f32 helpers (block FMA contraction / reassociation) ----
__device__ __forceinline__ float fmul32(float a, float b){ return __fmul_rn(a,b); }
__device__ __forceinline__ float fadd32(float a, float b){ return __fadd_rn(a,b); }
__device__ __forceinline__ float fsub32(float a, float b){ return __fsub_rn(a,b); }

// ---- per-thread insertion top-20 on f32 (largest, ties keep lowest index) ----
__device__ __forceinline__ void insert_candidatef(float v, int j,
                                                  float (&best)[K], int (&bidx)[K]) {
  if (v > best[K-1]) {
    best[K-1] = v; bidx[K-1] = j;
    #pragma unroll
    for (int i = K-1; i >= 1; --i) {
      if (best[i] > best[i-1]) {
        float tv = best[i]; best[i] = best[i-1]; best[i-1] = tv;
        int   ti = bidx[i]; bidx[i] = bidx[i-1]; bidx[i-1] = ti;
      }
    }
  }
}

// ---- kNN on 3-D coords, numpy-f32-faithful (BIT-FROZEN) ----
__global__ __launch_bounds__(64) void knn_xyz_f32(const float* __restrict__ x,
                                                  int* __restrict__ idxo) {
  int row = blockIdx.x * 64 + threadIdx.x;   // grid = B*N/64
  int b = row >> 11, n = row & (N - 1);
  const float* xb = x + (size_t)b * N * 3;
  float xi0 = xb[(size_t)n*3], xi1 = xb[(size_t)n*3+1], xi2 = xb[(size_t)n*3+2];
  float xxi = fadd32(fadd32(fmul32(xi0,xi0), fmul32(xi1,xi1)), fmul32(xi2,xi2));
  float best[K]; int bidx[K];
  #pragma unroll
  for (int i = 0; i < K; ++i) { best[i] = -INFINITY; bidx[i] = 0; }
  for (int j = 0; j < N; ++j) {
    float a = xb[(size_t)j*3], c = xb[(size_t)j*3+1], d = xb[(size_t)j*3+2];
    float xxj   = fadd32(fadd32(fmul32(a,a), fmul32(c,c)), fmul32(d,d));
    float inner = fadd32(fadd32(fmul32(xi0,a), fmul32(xi1,c)), fmul32(xi2,d));
    float v = fsub32(fsub32(fmul32(2.f, inner), xxi), xxj);
    insert_candidatef(v, j, best, bidx);
  }
  int* o = idxo + (size_t)row * K;
  #pragma unroll
  for (int i = 0; i < K; ++i) o[i] = bidx[i];
}

// ---- x2 -> f32 copy + numpy pairwise(n=128) sum of squares (BIT-FROZEN) ----
__global__ __launch_bounds__(64) void xx2f_kernel(const double* __restrict__ x2d,
                                                  float* __restrict__ x2f,
                                                  float* __restrict__ xx2f) {
  int row = blockIdx.x * 64 + threadIdx.x;   // grid = B*N/64
  const double* src = x2d + (size_t)row * C2;
  float* dst = x2f + (size_t)row * C2;
  float sq[C2];
  #pragma unroll 8
  for (int c = 0; c < C2; ++c) {
    float v = (float)src[c];
    dst[c] = v;
    sq[c] = fmul32(v, v);
  }
  float r0=sq[0], r1=sq[1], r2=sq[2], r3=sq[3], r4=sq[4], r5=sq[5], r6=sq[6], r7=sq[7];
  #pragma unroll
  for (int i = 8; i < 128; i += 8) {
    r0 = fadd32(r0, sq[i+0]); r1 = fadd32(r1, sq[i+1]);
    r2 = fadd32(r2, sq[i+2]); r3 = fadd32(r3, sq[i+3]);
    r4 = fadd32(r4, sq[i+4]); r5 = fadd32(r5, sq[i+5]);
    r6 = fadd32(r6, sq[i+6]); r7 = fadd32(r7, sq[i+7]);
  }
  xx2f[row] = fadd32(fadd32(fadd32(r0,r1), fadd32(r2,r3)),
                     fadd32(fadd32(r4,r5), fadd32(r6,r7)));
}

// ---- all-batch neg-distance matrix, f32 sequential (BIT-FROZEN inner) ----
__global__ __launch_bounds__(256) void dist_f32_kernel(const float* __restrict__ x2f,
                                                       const float* __restrict__ xx2f,
                                                       float* __restrict__ dist) {
  int bz = blockIdx.z;
  const float* x2b  = x2f  + (size_t)bz * N * C2;
  const float* xx2b = xx2f + (size_t)bz * N;
  float* db = dist + (size_t)bz * N * N;
  int ti = blockIdx.y * 64;
  int tj = blockIdx.x * 64;
  int tid = threadIdx.x;
  int tr = tid >> 4, tc = tid & 15;
  __shared__ float A[64][9], Bm[64][9];
  float acc[4][4];
  #pragma unroll
  for (int u = 0; u < 4; ++u)
    #pragma unroll
    for (int v = 0; v < 4; ++v) acc[u][v] = 0.f;
  for (int c0 = 0; c0 < C2; c0 += 8) {
    for (int i = tid; i < 512; i += 256) {
      int r = i >> 3, c = i & 7;
      A[r][c]  = x2b[(size_t)(ti + r)*C2 + c0 + c];
      Bm[r][c] = x2b[(size_t)(tj + r)*C2 + c0 + c];
    }
    __syncthreads();
    #pragma unroll
    for (int c = 0; c < 8; ++c) {       // ascending c: exact sequential order
      float a[4], bv[4];
      #pragma unroll
      for (int u = 0; u < 4; ++u) a[u] = A[tr*4 + u][c];
      #pragma unroll
      for (int v = 0; v < 4; ++v) bv[v] = Bm[tc*4 + v][c];
      #pragma unroll
      for (int u = 0; u < 4; ++u)
        #pragma unroll
        for (int v = 0; v < 4; ++v)
          acc[u][v] = fadd32(acc[u][v], fmul32(a[u], bv[v]));
    }
    __syncthreads();
  }
  #pragma unroll
  for (int u = 0; u < 4; ++u) {
    int i = ti + tr*4 + u;
    float xxi = xx2b[i];
    #pragma unroll
    for (int v = 0; v < 4; ++v) {
      int j = tj + tc*4 + v;
      db[(size_t)i*N + j] = fsub32(fsub32(fmul32(2.f, acc[u][v]), xxi), xx2b[j]);
    }
  }
}

// ---- wave-parallel top-20 on frozen dist values (coalesced reads) ----
__global__ __launch_bounds__(256) void knn_feat_wave(const float* __restrict__ dist,
                                                     int* __restrict__ idxo) {
  int row  = blockIdx.x * 4 + (threadIdx.x >> 6);   // grid = B*N/4
  int lane = threadIdx.x & 63;
  const float* dr = dist + (size_t)row * N;
  float vals[32];
  #pragma unroll
  for (int t = 0; t < 32; ++t) vals[t] = dr[lane + (t << 6)];   // coalesced
  int* out = idxo + (size_t)row * K;
  for (int sel = 0; sel < K; ++sel) {
    float best = -INFINITY; int bt = 0;
    #pragma unroll
    for (int t = 0; t < 32; ++t)
      if (vals[t] > best) { best = vals[t]; bt = t; }
    int bcol = lane + (bt << 6);
    #pragma unroll
    for (int off = 32; off >= 1; off >>= 1) {
      float ov = __shfl_xor(best, off, 64);
      int   oc = __shfl_xor(bcol, off, 64);
      if (ov > best || (ov == best && oc < bcol)) { best = ov; bcol = oc; }
    }
    if (lane == 0) out[sel] = bcol;
    int kill = ((bcol & 63) == lane) ? (bcol >> 6) : 32;
    #pragma unroll
    for (int t = 0; t < 32; ++t) if (t == kill) vals[t] = -INFINITY;
  }
}

// ---- layer 1 (two-pass, f64): geometry + conv1 (BIT-FROZEN) ----
template<int PASS>
__global__ __launch_bounds__(64) void l1_kernel(
    const float* __restrict__ x, const float* __restrict__ nrm,
    const float* __restrict__ w1, const int* __restrict__ idx1,
    double* __restrict__ sS, double* __restrict__ sQ,
    const double* __restrict__ mid, const float* __restrict__ g1, const float* __restrict__ b1,
    double* __restrict__ x1d, float* __restrict__ out448,
    float* __restrict__ outR1, float* __restrict__ outR2) {
  int p = blockIdx.x;
  int tid = threadIdx.x;
  int b = p >> 11, n = p & (N - 1);
  __shared__ float  wl[C1 * 9];
  __shared__ double rotd[K][3];
  __shared__ double fld[K][9];
  for (int i = tid; i < C1 * 9; i += 64) wl[i] = w1[i];
  const float* xb = x + (size_t)b * N * 3;
  double nx = nrm[(size_t)p*3], ny = nrm[(size_t)p*3+1], nz = nrm[(size_t)p*3+2];
  double vx = ny, vy = -nx;
  double s = 1.0 / fmax(1.0 + nz, 1e-8);
  double vxy = vx * vy;
  double R1v[9];
  R1v[0] = 1.0 - s*(vy*vy); R1v[1] = s*vxy;           R1v[2] = vy;
  R1v[3] = s*vxy;           R1v[4] = 1.0 - s*(vx*vx); R1v[5] = -vx;
  R1v[6] = -vy;             R1v[7] = vx;              R1v[8] = 1.0 - s*(vx*vx + vy*vy);
  double xi0 = xb[(size_t)n*3], xi1 = xb[(size_t)n*3+1], xi2 = xb[(size_t)n*3+2];
  if (tid < K) {
    int j = idx1[(size_t)p*K + tid];
    double d0 = (double)xb[(size_t)j*3]   - xi0;
    double d1 = (double)xb[(size_t)j*3+1] - xi1;
    double d2 = (double)xb[(size_t)j*3+2] - xi2;
    rotd[tid][0] = R1v[0]*d0 + R1v[1]*d1 + R1v[2]*d2;
    rotd[tid][1] = R1v[3]*d0 + R1v[4]*d1 + R1v[5]*d2;
    rotd[tid][2] = R1v[6]*d0 + R1v[7]*d1 + R1v[8]*d2;
  }
  __syncthreads();
  double mx = 0.0, my = 0.0;
  #pragma unroll
  for (int k = 0; k < K; ++k) { mx += rotd[k][0]; my += rotd[k][1]; }
  mx /= 20.0; my /= 20.0;
  double r = sqrt(mx*mx + my*my);
  double ct = 1.0, st = 0.0;
  if (r > 0.0) { ct = mx / r; st = my / r; }   // cos/sin of atan2(my,mx)
  if (tid < K) {
    double r0 = rotd[tid][0], r1 = rotd[tid][1], r2 = rotd[tid][2];
    double a0 = ct*r0 + st*r1;
    double a1 = ct*r1 - st*r0;
    fld[tid][0] = a0;  fld[tid][1] = a1;   fld[tid][2] = r2;
    fld[tid][3] = a0;  fld[tid][4] = -a1;  fld[tid][5] = r2;   // xz-mirror
    fld[tid][6] = xi0; fld[tid][7] = xi1;  fld[tid][8] = xi2;  // x_rep
  }
  if (PASS == 0 && tid == 0) {
    float* o1 = outR1 + (size_t)p * 9;
    #pragma unroll
    for (int i = 0; i < 9; ++i) o1[i] = (float)R1v[i];
    float* o2 = outR2 + (size_t)p * 9;
    o2[0] = (float)ct;  o2[1] = (float)st; o2[2] = 0.f;
    o2[3] = (float)-st; o2[4] = (float)ct; o2[5] = 0.f;
    o2[6] = 0.f;        o2[7] = 0.f;       o2[8] = 1.f;
  }
  __syncthreads();
  int o = tid;
  if (PASS == 0) {
    double sum = 0., sq = 0.;
    #pragma unroll
    for (int k = 0; k < K; ++k) {
      double h = 0.;
      #pragma unroll
      for (int c = 0; c < 9; ++c) h = fma((double)wl[o*9 + c], fld[k][c], h);
      sum += h; sq += h*h;
    }
    int slice = p & (NSLICE - 1);
    atomicAdd(&sS[slice*C3 + o], sum);
    atomicAdd(&sQ[slice*C3 + o], sq);
  } else {
    double m = mid[o], is = mid[C3 + o];
    double g = g1[o], bb = b1[o];
    double mxv = -INFINITY;
    #pragma unroll
    for (int k = 0; k < K; ++k) {
      double h = 0.;
      #pragma unroll
      for (int c = 0; c < 9; ++c) h = fma((double)wl[o*9 + c], fld[k][c], h);
      double y = ((h - m) * is) * g + bb;
      y = y > 0.0 ? y : 0.2 * y;
      mxv = fmax(mxv, y);
    }
    x1d[(size_t)p*C1 + o] = mxv;
    out448[(size_t)p*448 + o] = (float)mxv;
  }
}

// ---- conv2 core: r12-proven LDS op sequence, 128 threads (BIT-FROZEN) ----
__device__ __forceinline__ void conv2_core(const double* __restrict__ x1d,
                                           const int* __restrict__ idx,
                                           const float* __restrict__ w,
                                           int p, int tid, double (&acc)[K]) {
  int b = p >> 11;
  __shared__ double difL[K][C1];
  __shared__ double xiL[C1];
  __shared__ int jidx[K];
  if (tid < K) jidx[tid] = idx[(size_t)p*K + tid];
  if (tid < C1) xiL[tid] = x1d[(size_t)p*C1 + tid];
  __syncthreads();
  #pragma unroll 1
  for (int i = tid; i < K*C1; i += 128) {
    int k = i >> 6, c = i & 63;
    difL[k][c] = x1d[((size_t)b*N + jidx[k])*C1 + c] - xiL[c];
  }
  __syncthreads();
  const float* wr = w + (size_t)tid * (2*C1);
  #pragma unroll
  for (int k = 0; k < K; ++k) acc[k] = 0.0;
  // phase 1: diff operand, c ascending per acc
  #pragma unroll
  for (int c0 = 0; c0 < C1; c0 += 16) {
    double wd[16];
    #pragma unroll
    for (int i = 0; i < 16; ++i) wd[i] = (double)wr[c0+i];
    #pragma unroll
    for (int k = 0; k < K; ++k) {
      #pragma unroll
      for (int i = 0; i < 16; ++i) acc[k] = fma(wd[i], difL[k][c0+i], acc[k]);
    }
  }
  // phase 2: x_rep operand, c ascending per acc
  #pragma unroll
  for (int c0 = 0; c0 < C1; c0 += 16) {
    double wd[16], xiv[16];
    #pragma unroll
    for (int i = 0; i < 16; ++i) { wd[i] = (double)wr[C1+c0+i]; xiv[i] = xiL[c0+i]; }
    #pragma unroll
    for (int k = 0; k < K; ++k) {
      #pragma unroll
      for (int i = 0; i < 16; ++i) acc[k] = fma(wd[i], xiv[i], acc[k]);
    }
  }
}

// ---- conv2 (two-pass recompute, r12-proven) ----
template<int PASS>
__global__ __launch_bounds__(128, 1) void conv2_full(
    const double* __restrict__ x1d, const int* __restrict__ idx,
    const float* __restrict__ w,
    double* __restrict__ sS, double* __restrict__ sQ,
    const double* __restrict__ mid, const float* __restrict__ gam, const float* __restrict__ bet,
    double* __restrict__ x2d, float* __restrict__ out448) {
  int p = blockIdx.x;
  int tid = threadIdx.x;
  double acc[K];
  conv2_core(x1d, idx, w, p, tid, acc);
  if (PASS == 0) {
    double sum = 0., sq = 0.;
    #pragma unroll
    for (int k = 0; k < K; ++k) { sum += acc[k]; sq += acc[k]*acc[k]; }
    int slice = p & (NSLICE - 1);
    atomicAdd(&sS[slice*C3 + tid], sum);
    atomicAdd(&sQ[slice*C3 + tid], sq);
  } else {
    double m = mid[tid], is = mid[C3 + tid];
    double g = gam[tid], bb = bet[tid];
    double mxv = -INFINITY;
    #pragma unroll
    for (int k = 0; k < K; ++k) {
      double y = ((acc[k] - m) * is) * g + bb;
      y = y > 0.0 ? y : 0.2 * y;
      mxv = fmax(mxv, y);
    }
    x2d[(size_t)p*C2 + tid] = mxv;
    out448[(size_t)p*448 + C1 + tid] = (float)mxv;
  }
}

// ---- conv3 pass0 v4: r12 skeleton (acc[K], 256 thr, VGPR~80) with the k
// stream SPLIT across pipes: k=0..9 via LDS (5KB stage), k=10..19 via
// uniform-address global loads (readfirstlane row base -> one L2 req/instr).
// Operand values and per-acc fmaf order identical to r12 -> bit-same h3. ----
__global__ __launch_bounds__(256, 1) void conv3_p0_store(
    const float* __restrict__ x2f, const int* __restrict__ idx,
    const float* __restrict__ w,
    double* __restrict__ sS, double* __restrict__ sQ,
    __hip_bfloat16* __restrict__ h3) {
  int p = blockIdx.x;
  int tid = threadIdx.x;
  int b = p >> 11;
  __shared__ float xjL[10][C2];
  __shared__ float xiL[C2];
  __shared__ int jidx[K];
  if (tid < K) jidx[tid] = idx[(size_t)p*K + tid];
  if (tid < C2) xiL[tid] = x2f[(size_t)p*C2 + tid];
  __syncthreads();
  #pragma unroll 1
  for (int i = tid; i < 10*C2; i += 256) {
    int k = i >> 7, c = i & 127;
    xjL[k][c] = x2f[((size_t)b*N + jidx[k])*C2 + c];
  }
  int jr10[10];
  #pragma unroll
  for (int t = 0; t < 10; ++t)
    jr10[t] = __builtin_amdgcn_readfirstlane(jidx[10 + t]);
  __syncthreads();
  const float* wr = w + (size_t)tid * (2*C2);
  float base = 0.f;
  #pragma unroll
  for (int c0 = 0; c0 < C2; c0 += 32) {
    #pragma unroll
    for (int i = 0; i < 32; ++i)
      base = fmaf(wr[C2+c0+i] - wr[c0+i], xiL[c0+i], base);
  }
  float acc[K];
  #pragma unroll
  for (int k = 0; k < K; ++k) acc[k] = base;
  #pragma unroll
  for (int c0 = 0; c0 < C2; c0 += 32) {
    float wd[32];
    #pragma unroll
    for (int i = 0; i < 32; ++i) wd[i] = wr[c0+i];
    #pragma unroll
    for (int k = 0; k < 10; ++k) {
      #pragma unroll
      for (int i = 0; i < 32; ++i) acc[k] = fmaf(wd[i], xjL[k][c0+i], acc[k]);
    }
    #pragma unroll
    for (int t = 0; t < 10; ++t) {
      const float* rp = x2f + ((size_t)b*N + jr10[t])*C2 + c0;
      #pragma unroll
      for (int i = 0; i < 32; ++i) acc[10 + t] = fmaf(wd[i], rp[i], acc[10 + t]);
    }
  }
  double sum = 0., sq = 0.;
  __hip_bfloat16* hb = h3 + (size_t)p * K * C3;
  #pragma unroll
  for (int k = 0; k < K; ++k) {
    double h = (double)acc[k];
    sum += h; sq += h*h;
    hb[k*C3 + tid] = __float2bfloat16(acc[k]);
  }
  int slice = p & (NSLICE - 1);
  atomicAdd(&sS[slice*C3 + tid], sum);
  atomicAdd(&sQ[slice*C3 + tid], sq);
}

// ---- conv3 pass1: load bf16 h3 + BN + max (r11/r12-proven) ----
__global__ __launch_bounds__(256, 1) void conv3_p1_load(
    const __hip_bfloat16* __restrict__ h3, const double* __restrict__ mid,
    const float* __restrict__ gam, const float* __restrict__ bet,
    float* __restrict__ out448) {
  int p = blockIdx.x;
  int o = threadIdx.x;
  float m = (float)mid[o], is = (float)mid[C3 + o];
  float g = gam[o], bb = bet[o];
  const __hip_bfloat16* hb = h3 + (size_t)p * K * C3;
  float mxv = -INFINITY;
  #pragma unroll
  for (int k = 0; k < K; ++k) {
    float h = __bfloat162float(hb[k*C3 + o]);
    float y = (h - m) * is * g + bb;
    y = y > 0.f ? y : 0.2f * y;
    mxv = fmaxf(mxv, y);
  }
  out448[(size_t)p*448 + C1 + C2 + o] = mxv;
}

// ---- finalize BN stats (f64) ----
__global__ void finalize_stats(const double* __restrict__ sS, const double* __restrict__ sQ,
                               double* __restrict__ mid, int C) {
  int o = threadIdx.x;
  if (o >= C) return;
  double s = 0., q = 0.;
  for (int i = 0; i < NSLICE; ++i) { s += sS[i*C3 + o]; q += sQ[i*C3 + o]; }
  double m = s / COUNT;
  double v = q / COUNT - m*m;
  mid[o] = m;
  mid[C3 + o] = 1.0 / sqrt(v + BNEPS);
}

} // namespace

extern "C" void kernel_launch(void* const* d_in, const int* in_sizes, int n_in,
                              void* d_out, int out_size, void* d_ws, size_t ws_size,
                              hipStream_t stream) {
  (void)in_sizes; (void)n_in; (void)out_size; (void)ws_size;
  const float* x   = (const float*)d_in[0];
  const float* nrm = (const float*)d_in[1];
  const float* w1  = (const float*)d_in[2];
  const float* g1  = (const float*)d_in[3];
  const float* b1  = (const float*)d_in[4];
  const float* w2  = (const float*)d_in[5];
  const float* g2  = (const float*)d_in[6];
  const float* b2  = (const float*)d_in[7];
  const float* w3  = (const float*)d_in[8];
  const float* g3  = (const float*)d_in[9];
  const float* b3  = (const float*)d_in[10];
  float* out = (float*)d_out;
  char*  ws  = (char*)d_ws;

  int*    idx1 = (int*)(ws + OFF_IDX1);
  int*    idx2 = (int*)(ws + OFF_IDX2);
  double* x1d  = (double*)(ws + OFF_X1D);
  double* x2d  = (double*)(ws + OFF_X2D);
  double* sS   = (double*)(ws + OFF_STATS);
  double* sQ   = sS + (size_t)NSLICE * C3;
  double* mid  = (double*)(ws + OFF_MI);
  float*  x2f  = (float*)(ws + OFF_X2F);
  float*  xx2f = (float*)(ws + OFF_XX2F);
  char*   big  = ws + OFF_BIG;
  float*  dist = (float*)big;                 // live: dist_f32 .. knn_feat
  __hip_bfloat16* h3 = (__hip_bfloat16*)big;  // live: conv3_p0 .. conv3_p1 (dist dead)

  float* outR1 = out + (size_t)B * N * 448;
  float* outR2 = outR1 + (size_t)B * N * 9;

  // kNN1 — numpy-f32-faithful formula
  knn_xyz_f32<<<B*N/64, 64, 0, stream>>>(x, idx1);

  // layer 1 (f64 two-pass)
  hipMemsetAsync(sS, 0, (size_t)2*NSLICE*C3*sizeof(double), stream);
  l1_kernel<0><<<B*N, 64, 0, stream>>>(x, nrm, w1, idx1, sS, sQ, nullptr, nullptr, nullptr,
                                       nullptr, nullptr, outR1, outR2);
  finalize_stats<<<1, C3, 0, stream>>>(sS, sQ, mid, C1);
  l1_kernel<1><<<B*N, 64, 0, stream>>>(x, nrm, w1, idx1, nullptr, nullptr, mid, g1, b1,
                                       x1d, out, outR1, outR2);

  // layer 2 (f64 two-pass recompute, bit-exact op order)
  hipMemsetAsync(sS, 0, (size_t)2*NSLICE*C3*sizeof(double), stream);
  conv2_full<0><<<B*N, 128, 0, stream>>>(x1d, idx1, w2, sS, sQ, nullptr, nullptr, nullptr,
                                         nullptr, nullptr);
  finalize_stats<<<1, C3, 0, stream>>>(sS, sQ, mid, C2);
  conv2_full<1><<<B*N, 128, 0, stream>>>(x1d, idx1, w2, nullptr, nullptr, mid, g2, b2,
                                         x2d, out);

  // kNN2 — numpy-f32-faithful, all batches fused; wave-parallel coalesced top-k
  xx2f_kernel<<<B*N/64, 64, 0, stream>>>(x2d, x2f, xx2f);
  dist_f32_kernel<<<dim3(N/64, N/64, B), 256, 0, stream>>>(x2f, xx2f, dist);
  knn_feat_wave<<<B*N/4, 256, 0, stream>>>(dist, idx2);

  // layer 3 (f32 conv once, dual-pipe operand streams + bf16 h3 + light BN/max)
  hipMemsetAsync(sS, 0, (size_t)2*NSLICE*C3*sizeof(double), stream);
  conv3_p0_store<<<B*N, 256, 0, stream>>>(x2f, idx2, w3, sS, sQ, h3);
  finalize_stats<<<1, C3, 0, stream>>>(sS, sQ, mid, C3);
  conv3_p1_load<<<B*N, 256, 0, stream>>>(h3, mid, g3, b3, out);
}

// Round 15
// 1954.337 us; speedup vs baseline: 1.5838x; 1.1374x over previous
//
#include <hip/hip_runtime.h>
#include <hip/hip_bf16.h>
#include <math.h>

namespace {

constexpr int B  = 8;
constexpr int N  = 2048;     // power of two: n = p & 2047, b = p >> 11
constexpr int K  = 20;
constexpr int C1 = 64, C2 = 128, C3 = 256;
constexpr int NSLICE = 64;
constexpr double COUNT = 327680.0;   // B*N*K
constexpr double BNEPS = 1e-5;

// ---- workspace layout (bytes) ----
constexpr size_t OFF_IDX1  = 0;                                  // B*N*K int
constexpr size_t OFF_IDX2  = OFF_IDX1 + (size_t)B*N*K*4;         // B*N*K int
constexpr size_t OFF_X1D   = OFF_IDX2 + (size_t)B*N*K*4;         // B*N*C1 f64
constexpr size_t OFF_X2D   = OFF_X1D  + (size_t)B*N*C1*8;        // B*N*C2 f64
constexpr size_t OFF_STATS = OFF_X2D  + (size_t)B*N*C2*8;        // 2*NSLICE*C3 f64
constexpr size_t OFF_MI    = OFF_STATS+ (size_t)2*NSLICE*C3*8;   // 2*C3 f64
constexpr size_t OFF_X2F   = OFF_MI   + 4096;                    // B*N*C2 f32
constexpr size_t OFF_XX2F  = OFF_X2F  + (size_t)B*N*C2*4;        // B*N f32
constexpr size_t OFF_BIG   = OFF_XX2F + (size_t)B*N*4;           // shared big region
// big region, sequential lifetimes (all within proven r11/r12 footprint):
//   {hmax2,hmin2 f64: 2 x 16.8 MB}  ->  dist f32 (134.2 MB)  ->  {hmax3,hmin3 f32: 2 x 8.4 MB}

// ---- strict-rounding f32 helpers (block FMA contraction / reassociation) ----
__device__ __forceinline__ float fmul32(float a, float b){ return __fmul_rn(a,b); }
__device__ __forceinline__ float fadd32(float a, float b){ return __fadd_rn(a,b); }
__device__ __forceinline__ float fsub32(float a, float b){ return __fsub_rn(a,b); }

// ---- per-thread insertion top-20 on f32 (largest, ties keep lowest index) ----
__device__ __forceinline__ void insert_candidatef(float v, int j,
                                                  float (&best)[K], int (&bidx)[K]) {
  if (v > best[K-1]) {
    best[K-1] = v; bidx[K-1] = j;
    #pragma unroll
    for (int i = K-1; i >= 1; --i) {
      if (best[i] > best[i-1]) {
        float tv = best[i]; best[i] = best[i-1]; best[i-1] = tv;
        int   ti = bidx[i]; bidx[i] = bidx[i-1]; bidx[i-1] = ti;
      }
    }
  }
}

// ---- kNN on 3-D coords, numpy-f32-faithful (BIT-FROZEN) ----
__global__ __launch_bounds__(64) void knn_xyz_f32(const float* __restrict__ x,
                                                  int* __restrict__ idxo) {
  int row = blockIdx.x * 64 + threadIdx.x;   // grid = B*N/64
  int b = row >> 11, n = row & (N - 1);
  const float* xb = x + (size_t)b * N * 3;
  float xi0 = xb[(size_t)n*3], xi1 = xb[(size_t)n*3+1], xi2 = xb[(size_t)n*3+2];
  float xxi = fadd32(fadd32(fmul32(xi0,xi0), fmul32(xi1,xi1)), fmul32(xi2,xi2));
  float best[K]; int bidx[K];
  #pragma unroll
  for (int i = 0; i < K; ++i) { best[i] = -INFINITY; bidx[i] = 0; }
  for (int j = 0; j < N; ++j) {
    float a = xb[(size_t)j*3], c = xb[(size_t)j*3+1], d = xb[(size_t)j*3+2];
    float xxj   = fadd32(fadd32(fmul32(a,a), fmul32(c,c)), fmul32(d,d));
    float inner = fadd32(fadd32(fmul32(xi0,a), fmul32(xi1,c)), fmul32(xi2,d));
    float v = fsub32(fsub32(fmul32(2.f, inner), xxi), xxj);
    insert_candidatef(v, j, best, bidx);
  }
  int* o = idxo + (size_t)row * K;
  #pragma unroll
  for (int i = 0; i < K; ++i) o[i] = bidx[i];
}

// ---- x2 -> f32 copy + numpy pairwise(n=128) sum of squares (BIT-FROZEN) ----
__global__ __launch_bounds__(64) void xx2f_kernel(const double* __restrict__ x2d,
                                                  float* __restrict__ x2f,
                                                  float* __restrict__ xx2f) {
  int row = blockIdx.x * 64 + threadIdx.x;   // grid = B*N/64
  const double* src = x2d + (size_t)row * C2;
  float* dst = x2f + (size_t)row * C2;
  float sq[C2];
  #pragma unroll 8
  for (int c = 0; c < C2; ++c) {
    float v = (float)src[c];
    dst[c] = v;
    sq[c] = fmul32(v, v);
  }
  float r0=sq[0], r1=sq[1], r2=sq[2], r3=sq[3], r4=sq[4], r5=sq[5], r6=sq[6], r7=sq[7];
  #pragma unroll
  for (int i = 8; i < 128; i += 8) {
    r0 = fadd32(r0, sq[i+0]); r1 = fadd32(r1, sq[i+1]);
    r2 = fadd32(r2, sq[i+2]); r3 = fadd32(r3, sq[i+3]);
    r4 = fadd32(r4, sq[i+4]); r5 = fadd32(r5, sq[i+5]);
    r6 = fadd32(r6, sq[i+6]); r7 = fadd32(r7, sq[i+7]);
  }
  xx2f[row] = fadd32(fadd32(fadd32(r0,r1), fadd32(r2,r3)),
                     fadd32(fadd32(r4,r5), fadd32(r6,r7)));
}

// ---- all-batch neg-distance matrix, f32 sequential (BIT-FROZEN inner) ----
__global__ __launch_bounds__(256) void dist_f32_kernel(const float* __restrict__ x2f,
                                                       const float* __restrict__ xx2f,
                                                       float* __restrict__ dist) {
  int bz = blockIdx.z;
  const float* x2b  = x2f  + (size_t)bz * N * C2;
  const float* xx2b = xx2f + (size_t)bz * N;
  float* db = dist + (size_t)bz * N * N;
  int ti = blockIdx.y * 64;
  int tj = blockIdx.x * 64;
  int tid = threadIdx.x;
  int tr = tid >> 4, tc = tid & 15;
  __shared__ float A[64][9], Bm[64][9];
  float acc[4][4];
  #pragma unroll
  for (int u = 0; u < 4; ++u)
    #pragma unroll
    for (int v = 0; v < 4; ++v) acc[u][v] = 0.f;
  for (int c0 = 0; c0 < C2; c0 += 8) {
    for (int i = tid; i < 512; i += 256) {
      int r = i >> 3, c = i & 7;
      A[r][c]  = x2b[(size_t)(ti + r)*C2 + c0 + c];
      Bm[r][c] = x2b[(size_t)(tj + r)*C2 + c0 + c];
    }
    __syncthreads();
    #pragma unroll
    for (int c = 0; c < 8; ++c) {       // ascending c: exact sequential order
      float a[4], bv[4];
      #pragma unroll
      for (int u = 0; u < 4; ++u) a[u] = A[tr*4 + u][c];
      #pragma unroll
      for (int v = 0; v < 4; ++v) bv[v] = Bm[tc*4 + v][c];
      #pragma unroll
      for (int u = 0; u < 4; ++u)
        #pragma unroll
        for (int v = 0; v < 4; ++v)
          acc[u][v] = fadd32(acc[u][v], fmul32(a[u], bv[v]));
    }
    __syncthreads();
  }
  #pragma unroll
  for (int u = 0; u < 4; ++u) {
    int i = ti + tr*4 + u;
    float xxi = xx2b[i];
    #pragma unroll
    for (int v = 0; v < 4; ++v) {
      int j = tj + tc*4 + v;
      db[(size_t)i*N + j] = fsub32(fsub32(fmul32(2.f, acc[u][v]), xxi), xx2b[j]);
    }
  }
}

// ---- wave-parallel top-20 on frozen dist values (coalesced reads) ----
__global__ __launch_bounds__(256) void knn_feat_wave(const float* __restrict__ dist,
                                                     int* __restrict__ idxo) {
  int row  = blockIdx.x * 4 + (threadIdx.x >> 6);   // grid = B*N/4
  int lane = threadIdx.x & 63;
  const float* dr = dist + (size_t)row * N;
  float vals[32];
  #pragma unroll
  for (int t = 0; t < 32; ++t) vals[t] = dr[lane + (t << 6)];   // coalesced
  int* out = idxo + (size_t)row * K;
  for (int sel = 0; sel < K; ++sel) {
    float best = -INFINITY; int bt = 0;
    #pragma unroll
    for (int t = 0; t < 32; ++t)
      if (vals[t] > best) { best = vals[t]; bt = t; }
    int bcol = lane + (bt << 6);
    #pragma unroll
    for (int off = 32; off >= 1; off >>= 1) {
      float ov = __shfl_xor(best, off, 64);
      int   oc = __shfl_xor(bcol, off, 64);
      if (ov > best || (ov == best && oc < bcol)) { best = ov; bcol = oc; }
    }
    if (lane == 0) out[sel] = bcol;
    int kill = ((bcol & 63) == lane) ? (bcol >> 6) : 32;
    #pragma unroll
    for (int t = 0; t < 32; ++t) if (t == kill) vals[t] = -INFINITY;
  }
}

// ---- layer 1 (two-pass, f64): geometry + conv1 (BIT-FROZEN) ----
template<int PASS>
__global__ __launch_bounds__(64) void l1_kernel(
    const float* __restrict__ x, const float* __restrict__ nrm,
    const float* __restrict__ w1, const int* __restrict__ idx1,
    double* __restrict__ sS, double* __restrict__ sQ,
    const double* __restrict__ mid, const float* __restrict__ g1, const float* __restrict__ b1,
    double* __restrict__ x1d, float* __restrict__ out448,
    float* __restrict__ outR1, float* __restrict__ outR2) {
  int p = blockIdx.x;
  int tid = threadIdx.x;
  int b = p >> 11, n = p & (N - 1);
  __shared__ float  wl[C1 * 9];
  __shared__ double rotd[K][3];
  __shared__ double fld[K][9];
  for (int i = tid; i < C1 * 9; i += 64) wl[i] = w1[i];
  const float* xb = x + (size_t)b * N * 3;
  double nx = nrm[(size_t)p*3], ny = nrm[(size_t)p*3+1], nz = nrm[(size_t)p*3+2];
  double vx = ny, vy = -nx;
  double s = 1.0 / fmax(1.0 + nz, 1e-8);
  double vxy = vx * vy;
  double R1v[9];
  R1v[0] = 1.0 - s*(vy*vy); R1v[1] = s*vxy;           R1v[2] = vy;
  R1v[3] = s*vxy;           R1v[4] = 1.0 - s*(vx*vx); R1v[5] = -vx;
  R1v[6] = -vy;             R1v[7] = vx;              R1v[8] = 1.0 - s*(vx*vx + vy*vy);
  double xi0 = xb[(size_t)n*3], xi1 = xb[(size_t)n*3+1], xi2 = xb[(size_t)n*3+2];
  if (tid < K) {
    int j = idx1[(size_t)p*K + tid];
    double d0 = (double)xb[(size_t)j*3]   - xi0;
    double d1 = (double)xb[(size_t)j*3+1] - xi1;
    double d2 = (double)xb[(size_t)j*3+2] - xi2;
    rotd[tid][0] = R1v[0]*d0 + R1v[1]*d1 + R1v[2]*d2;
    rotd[tid][1] = R1v[3]*d0 + R1v[4]*d1 + R1v[5]*d2;
    rotd[tid][2] = R1v[6]*d0 + R1v[7]*d1 + R1v[8]*d2;
  }
  __syncthreads();
  double mx = 0.0, my = 0.0;
  #pragma unroll
  for (int k = 0; k < K; ++k) { mx += rotd[k][0]; my += rotd[k][1]; }
  mx /= 20.0; my /= 20.0;
  double r = sqrt(mx*mx + my*my);
  double ct = 1.0, st = 0.0;
  if (r > 0.0) { ct = mx / r; st = my / r; }   // cos/sin of atan2(my,mx)
  if (tid < K) {
    double r0 = rotd[tid][0], r1 = rotd[tid][1], r2 = rotd[tid][2];
    double a0 = ct*r0 + st*r1;
    double a1 = ct*r1 - st*r0;
    fld[tid][0] = a0;  fld[tid][1] = a1;   fld[tid][2] = r2;
    fld[tid][3] = a0;  fld[tid][4] = -a1;  fld[tid][5] = r2;   // xz-mirror
    fld[tid][6] = xi0; fld[tid][7] = xi1;  fld[tid][8] = xi2;  // x_rep
  }
  if (PASS == 0 && tid == 0) {
    float* o1 = outR1 + (size_t)p * 9;
    #pragma unroll
    for (int i = 0; i < 9; ++i) o1[i] = (float)R1v[i];
    float* o2 = outR2 + (size_t)p * 9;
    o2[0] = (float)ct;  o2[1] = (float)st; o2[2] = 0.f;
    o2[3] = (float)-st; o2[4] = (float)ct; o2[5] = 0.f;
    o2[6] = 0.f;        o2[7] = 0.f;       o2[8] = 1.f;
  }
  __syncthreads();
  int o = tid;
  if (PASS == 0) {
    double sum = 0., sq = 0.;
    #pragma unroll
    for (int k = 0; k < K; ++k) {
      double h = 0.;
      #pragma unroll
      for (int c = 0; c < 9; ++c) h = fma((double)wl[o*9 + c], fld[k][c], h);
      sum += h; sq += h*h;
    }
    int slice = p & (NSLICE - 1);
    atomicAdd(&sS[slice*C3 + o], sum);
    atomicAdd(&sQ[slice*C3 + o], sq);
  } else {
    double m = mid[o], is = mid[C3 + o];
    double g = g1[o], bb = b1[o];
    double mxv = -INFINITY;
    #pragma unroll
    for (int k = 0; k < K; ++k) {
      double h = 0.;
      #pragma unroll
      for (int c = 0; c < 9; ++c) h = fma((double)wl[o*9 + c], fld[k][c], h);
      double y = ((h - m) * is) * g + bb;
      y = y > 0.0 ? y : 0.2 * y;
      mxv = fmax(mxv, y);
    }
    x1d[(size_t)p*C1 + o] = mxv;
    out448[(size_t)p*448 + o] = (float)mxv;
  }
}

// ---- conv2 core: r12-proven LDS op sequence, 128 threads (BIT-FROZEN) ----
__device__ __forceinline__ void conv2_core(const double* __restrict__ x1d,
                                           const int* __restrict__ idx,
                                           const float* __restrict__ w,
                                           int p, int tid, double (&acc)[K]) {
  int b = p >> 11;
  __shared__ double difL[K][C1];
  __shared__ double xiL[C1];
  __shared__ int jidx[K];
  if (tid < K) jidx[tid] = idx[(size_t)p*K + tid];
  if (tid < C1) xiL[tid] = x1d[(size_t)p*C1 + tid];
  __syncthreads();
  #pragma unroll 1
  for (int i = tid; i < K*C1; i += 128) {
    int k = i >> 6, c = i & 63;
    difL[k][c] = x1d[((size_t)b*N + jidx[k])*C1 + c] - xiL[c];
  }
  __syncthreads();
  const float* wr = w + (size_t)tid * (2*C1);
  #pragma unroll
  for (int k = 0; k < K; ++k) acc[k] = 0.0;
  // phase 1: diff operand, c ascending per acc
  #pragma unroll
  for (int c0 = 0; c0 < C1; c0 += 16) {
    double wd[16];
    #pragma unroll
    for (int i = 0; i < 16; ++i) wd[i] = (double)wr[c0+i];
    #pragma unroll
    for (int k = 0; k < K; ++k) {
      #pragma unroll
      for (int i = 0; i < 16; ++i) acc[k] = fma(wd[i], difL[k][c0+i], acc[k]);
    }
  }
  // phase 2: x_rep operand, c ascending per acc
  #pragma unroll
  for (int c0 = 0; c0 < C1; c0 += 16) {
    double wd[16], xiv[16];
    #pragma unroll
    for (int i = 0; i < 16; ++i) { wd[i] = (double)wr[C1+c0+i]; xiv[i] = xiL[c0+i]; }
    #pragma unroll
    for (int k = 0; k < K; ++k) {
      #pragma unroll
      for (int i = 0; i < 16; ++i) acc[k] = fma(wd[i], xiv[i], acc[k]);
    }
  }
}

// ---- conv2 pass0: conv ONCE + stats + hmax/hmin (f64) store ----
__global__ __launch_bounds__(128, 1) void conv2_p0(
    const double* __restrict__ x1d, const int* __restrict__ idx,
    const float* __restrict__ w,
    double* __restrict__ sS, double* __restrict__ sQ,
    double* __restrict__ hmx2, double* __restrict__ hmn2) {
  int p = blockIdx.x;
  int tid = threadIdx.x;
  double acc[K];
  conv2_core(x1d, idx, w, p, tid, acc);
  double sum = 0., sq = 0., hmx = -INFINITY, hmn = INFINITY;
  #pragma unroll
  for (int k = 0; k < K; ++k) {
    sum += acc[k]; sq += acc[k]*acc[k];
    hmx = fmax(hmx, acc[k]); hmn = fmin(hmn, acc[k]);
  }
  hmx2[(size_t)p*C2 + tid] = hmx;
  hmn2[(size_t)p*C2 + tid] = hmn;
  int slice = p & (NSLICE - 1);
  atomicAdd(&sS[slice*C3 + tid], sum);
  atomicAdd(&sQ[slice*C3 + tid], sq);
}

// ---- conv2 pass1 (light): BN+LReLU at h extremes; max = fmax of the two.
// Monotone affine + monotone LReLU (f64 rounding monotone) -> bit-identical
// to the k-loop fmax over all y_k. ----
__global__ __launch_bounds__(256) void conv2_p1_light(
    const double* __restrict__ hmx2, const double* __restrict__ hmn2,
    const double* __restrict__ mid, const float* __restrict__ gam,
    const float* __restrict__ bet,
    double* __restrict__ x2d, float* __restrict__ out448) {
  int i = blockIdx.x * 256 + threadIdx.x;   // grid = B*N*C2/256
  int p = i >> 7, o = i & 127;
  double m = mid[o], is = mid[C3 + o];
  double g = gam[o], bb = bet[o];
  double y1 = ((hmx2[i] - m) * is) * g + bb;
  y1 = y1 > 0.0 ? y1 : 0.2 * y1;
  double y2 = ((hmn2[i] - m) * is) * g + bb;
  y2 = y2 > 0.0 ? y2 : 0.2 * y2;
  double mxv = fmax(y1, y2);
  x2d[i] = mxv;
  out448[(size_t)p*448 + C1 + o] = (float)mxv;
}

// ---- conv3 pass0: r12-proven skeleton (256 thr, acc[K], VGPR~80) — conv
// ONCE + stats + f32 hmax/hmin store (no h3 buffer at all). ----
__global__ __launch_bounds__(256, 1) void conv3_p0(
    const float* __restrict__ x2f, const int* __restrict__ idx,
    const float* __restrict__ w,
    double* __restrict__ sS, double* __restrict__ sQ,
    float* __restrict__ hmx3, float* __restrict__ hmn3) {
  int p = blockIdx.x;
  int tid = threadIdx.x;
  int b = p >> 11;
  __shared__ float xjL[K][C2];
  __shared__ float xiL[C2];
  __shared__ int jidx[K];
  if (tid < K) jidx[tid] = idx[(size_t)p*K + tid];
  if (tid < C2) xiL[tid] = x2f[(size_t)p*C2 + tid];
  __syncthreads();
  #pragma unroll 1
  for (int i = tid; i < K*C2; i += 256) {
    int k = i >> 7, c = i & 127;
    xjL[k][c] = x2f[((size_t)b*N + jidx[k])*C2 + c];
  }
  __syncthreads();
  const float* wr = w + (size_t)tid * (2*C2);
  float base = 0.f;
  #pragma unroll
  for (int c0 = 0; c0 < C2; c0 += 32) {
    #pragma unroll
    for (int i = 0; i < 32; ++i)
      base = fmaf(wr[C2+c0+i] - wr[c0+i], xiL[c0+i], base);
  }
  float acc[K];
  #pragma unroll
  for (int k = 0; k < K; ++k) acc[k] = base;
  #pragma unroll
  for (int c0 = 0; c0 < C2; c0 += 32) {
    float wd[32];
    #pragma unroll
    for (int i = 0; i < 32; ++i) wd[i] = wr[c0+i];
    #pragma unroll
    for (int k = 0; k < K; ++k) {
      #pragma unroll
      for (int i = 0; i < 32; ++i) acc[k] = fmaf(wd[i], xjL[k][c0+i], acc[k]);
    }
  }
  double sum = 0., sq = 0.;
  float hmx = -INFINITY, hmn = INFINITY;
  #pragma unroll
  for (int k = 0; k < K; ++k) {
    double h = (double)acc[k];
    sum += h; sq += h*h;
    hmx = fmaxf(hmx, acc[k]); hmn = fminf(hmn, acc[k]);
  }
  hmx3[(size_t)p*C3 + tid] = hmx;
  hmn3[(size_t)p*C3 + tid] = hmn;
  int slice = p & (NSLICE - 1);
  atomicAdd(&sS[slice*C3 + tid], sum);
  atomicAdd(&sQ[slice*C3 + tid], sq);
}

// ---- conv3 pass1 (light): BN+LReLU at extremes, fmax -> out ----
__global__ __launch_bounds__(256) void conv3_p1_light(
    const float* __restrict__ hmx3, const float* __restrict__ hmn3,
    const double* __restrict__ mid, const float* __restrict__ gam,
    const float* __restrict__ bet, float* __restrict__ out448) {
  int i = blockIdx.x * 256 + threadIdx.x;   // grid = B*N*C3/256
  int p = i >> 8, o = i & 255;
  float m = (float)mid[o], is = (float)mid[C3 + o];
  float g = gam[o], bb = bet[o];
  float y1 = (hmx3[i] - m) * is * g + bb;
  y1 = y1 > 0.f ? y1 : 0.2f * y1;
  float y2 = (hmn3[i] - m) * is * g + bb;
  y2 = y2 > 0.f ? y2 : 0.2f * y2;
  out448[(size_t)p*448 + C1 + C2 + o] = fmaxf(y1, y2);
}

// ---- finalize BN stats (f64) ----
__global__ void finalize_stats(const double* __restrict__ sS, const double* __restrict__ sQ,
                               double* __restrict__ mid, int C) {
  int o = threadIdx.x;
  if (o >= C) return;
  double s = 0., q = 0.;
  for (int i = 0; i < NSLICE; ++i) { s += sS[i*C3 + o]; q += sQ[i*C3 + o]; }
  double m = s / COUNT;
  double v = q / COUNT - m*m;
  mid[o] = m;
  mid[C3 + o] = 1.0 / sqrt(v + BNEPS);
}

} // namespace

extern "C" void kernel_launch(void* const* d_in, const int* in_sizes, int n_in,
                              void* d_out, int out_size, void* d_ws, size_t ws_size,
                              hipStream_t stream) {
  (void)in_sizes; (void)n_in; (void)out_size; (void)ws_size;
  const float* x   = (const float*)d_in[0];
  const float* nrm = (const float*)d_in[1];
  const float* w1  = (const float*)d_in[2];
  const float* g1  = (const float*)d_in[3];
  const float* b1  = (const float*)d_in[4];
  const float* w2  = (const float*)d_in[5];
  const float* g2  = (const float*)d_in[6];
  const float* b2  = (const float*)d_in[7];
  const float* w3  = (const float*)d_in[8];
  const float* g3  = (const float*)d_in[9];
  const float* b3  = (const float*)d_in[10];
  float* out = (float*)d_out;
  char*  ws  = (char*)d_ws;

  int*    idx1 = (int*)(ws + OFF_IDX1);
  int*    idx2 = (int*)(ws + OFF_IDX2);
  double* x1d  = (double*)(ws + OFF_X1D);
  double* x2d  = (double*)(ws + OFF_X2D);
  double* sS   = (double*)(ws + OFF_STATS);
  double* sQ   = sS + (size_t)NSLICE * C3;
  double* mid  = (double*)(ws + OFF_MI);
  float*  x2f  = (float*)(ws + OFF_X2F);
  float*  xx2f = (float*)(ws + OFF_XX2F);
  char*   big  = ws + OFF_BIG;
  // sequential lifetimes within big:
  double* hmx2 = (double*)big;                                   // conv2_p0..p1
  double* hmn2 = hmx2 + (size_t)B*N*C2;
  float*  dist = (float*)big;                                    // dist..knn_feat
  float*  hmx3 = (float*)big;                                    // conv3_p0..p1
  float*  hmn3 = hmx3 + (size_t)B*N*C3;

  float* outR1 = out + (size_t)B * N * 448;
  float* outR2 = outR1 + (size_t)B * N * 9;

  // kNN1 — numpy-f32-faithful formula
  knn_xyz_f32<<<B*N/64, 64, 0, stream>>>(x, idx1);

  // layer 1 (f64 two-pass)
  hipMemsetAsync(sS, 0, (size_t)2*NSLICE*C3*sizeof(double), stream);
  l1_kernel<0><<<B*N, 64, 0, stream>>>(x, nrm, w1, idx1, sS, sQ, nullptr, nullptr, nullptr,
                                       nullptr, nullptr, outR1, outR2);
  finalize_stats<<<1, C3, 0, stream>>>(sS, sQ, mid, C1);
  l1_kernel<1><<<B*N, 64, 0, stream>>>(x, nrm, w1, idx1, nullptr, nullptr, mid, g1, b1,
                                       x1d, out, outR1, outR2);

  // layer 2: conv once (bit-frozen core) + extremes; light BN finish
  hipMemsetAsync(sS, 0, (size_t)2*NSLICE*C3*sizeof(double), stream);
  conv2_p0<<<B*N, 128, 0, stream>>>(x1d, idx1, w2, sS, sQ, hmx2, hmn2);
  finalize_stats<<<1, C3, 0, stream>>>(sS, sQ, mid, C2);
  conv2_p1_light<<<B*N*C2/256, 256, 0, stream>>>(hmx2, hmn2, mid, g2, b2, x2d, out);

  // kNN2 — numpy-f32-faithful, all batches fused; wave-parallel coalesced top-k
  xx2f_kernel<<<B*N/64, 64, 0, stream>>>(x2d, x2f, xx2f);
  dist_f32_kernel<<<dim3(N/64, N/64, B), 256, 0, stream>>>(x2f, xx2f, dist);
  knn_feat_wave<<<B*N/4, 256, 0, stream>>>(dist, idx2);

  // layer 3: conv once (f32, r12 skeleton) + extremes; light BN finish
  hipMemsetAsync(sS, 0, (size_t)2*NSLICE*C3*sizeof(double), stream);
  conv3_p0<<<B*N, 256, 0, stream>>>(x2f, idx2, w3, sS, sQ, hmx3, hmn3);
  finalize_stats<<<1, C3, 0, stream>>>(sS, sQ, mid, C3);
  conv3_p1_light<<<B*N*C3/256, 256, 0, stream>>>(hmx3, hmn3, mid, g3, b3, out);
}